// Round 3
// baseline (1353.035 us; speedup 1.0000x reference)
//
#include <hip/hip_runtime.h>
#include <hip/hip_bf16.h>

typedef __attribute__((ext_vector_type(8))) short bf16x8;
typedef __attribute__((ext_vector_type(4))) float f32x4;

#define EPSV 1e-5f

#define NN 50000
#define NE 800000
#define NG 64

__device__ __forceinline__ unsigned short f2bf(float f) {
  union { float f; unsigned u; } v; v.f = f;
  unsigned r = v.u + 0x7FFFu + ((v.u >> 16) & 1u);
  return (unsigned short)(r >> 16);
}

// ---------------- conversion kernels ----------------

__global__ __launch_bounds__(256) void cvt_vec_kernel(
    const float* __restrict__ x, const float* __restrict__ e,
    unsigned short* __restrict__ xb, unsigned short* __restrict__ eb) {
  const int NX4 = (NN * 128) / 4;     // 1,600,000
  const int NE4 = (NE * 32) / 4;      // 6,400,000
  const int total = NX4 + NE4;
  for (int idx = blockIdx.x * 256 + threadIdx.x; idx < total;
       idx += gridDim.x * 256) {
    float4 v = (idx < NX4) ? ((const float4*)x)[idx]
                           : ((const float4*)e)[idx - NX4];
    ushort4 o;
    o.x = f2bf(v.x); o.y = f2bf(v.y); o.z = f2bf(v.z); o.w = f2bf(v.w);
    if (idx < NX4) ((ushort4*)xb)[idx] = o;
    else           ((ushort4*)eb)[idx - NX4] = o;
  }
}

__global__ __launch_bounds__(256) void cvt_small_kernel(
    const float* __restrict__ u,
    const float* __restrict__ eW1, const float* __restrict__ eW2,
    const float* __restrict__ nW1, const float* __restrict__ nW2,
    unsigned short* __restrict__ ub,
    unsigned short* __restrict__ eW1T, unsigned short* __restrict__ eW2T,
    unsigned short* __restrict__ nW1T, unsigned short* __restrict__ nW2T) {
  int i = blockIdx.x * 256 + threadIdx.x;
  const int R0 = NG * 32;          // 2048 : ub
  const int R1 = R0 + 128 * 320;   // eW1T  (K=320)
  const int R2 = R1 + 128 * 128;   // eW2T
  const int R3 = R2 + 128 * 320;   // nW1T  (K padded 288->320)
  const int R4 = R3 + 128 * 128;   // nW2T
  if (i < R0) {
    ub[i] = f2bf(u[i]);
  } else if (i < R1) {
    int j = i - R0; int n = j / 320, k = j % 320;
    eW1T[j] = f2bf(eW1[k * 128 + n]);
  } else if (i < R2) {
    int j = i - R1; int n = j / 128, k = j % 128;
    eW2T[j] = f2bf(eW2[k * 128 + n]);
  } else if (i < R3) {
    int j = i - R2; int n = j / 320, k = j % 320;
    nW1T[j] = (k < 288) ? f2bf(nW1[k * 128 + n]) : (unsigned short)0;
  } else if (i < R4) {
    int j = i - R3; int n = j / 128, k = j % 128;
    nW2T[j] = f2bf(nW2[k * 128 + n]);
  }
}

// ---------------- CSR construction ----------------

// histogram of receivers + edge graph-id precompute
__global__ __launch_bounds__(256) void pre_kernel(
    const int* __restrict__ rowIdx, const int* __restrict__ colIdx,
    const int* __restrict__ batch, int* __restrict__ eg_arr,
    int* __restrict__ cnt) {
  int i = blockIdx.x * 256 + threadIdx.x;
  if (i < NE) {
    eg_arr[i] = batch[rowIdx[i]];
    atomicAdd(&cnt[colIdx[i]], 1);
  }
}

// single-block exclusive scan over 50000 counts (register-segmented)
__global__ __launch_bounds__(1024) void scan_kernel(
    const int* __restrict__ cnt, int* __restrict__ offs,
    int* __restrict__ cur) {
  __shared__ int sums[1024];
  const int t = threadIdx.x;
  const int base = t * 49;   // 1024*49 = 50176 >= NN
  int s = 0;
  for (int j = 0; j < 49; ++j) {
    int idx = base + j;
    if (idx < NN) s += cnt[idx];
  }
  sums[t] = s;
  __syncthreads();
  for (int off = 1; off < 1024; off <<= 1) {
    int add = (t >= off) ? sums[t - off] : 0;
    __syncthreads();
    sums[t] += add;
    __syncthreads();
  }
  int run = (t == 0) ? 0 : sums[t - 1];
  for (int j = 0; j < 49; ++j) {
    int idx = base + j;
    if (idx < NN) {
      offs[idx] = run; cur[idx] = run;
      run += cnt[idx];
    }
  }
}

__global__ __launch_bounds__(256) void fill_kernel(
    const int* __restrict__ colIdx, int* __restrict__ cur,
    int* __restrict__ eidlist) {
  int i = blockIdx.x * 256 + threadIdx.x;
  if (i < NE) {
    int p = atomicAdd(&cur[colIdx[i]], 1);
    eidlist[p] = i;
  }
}

// ---------------- fused MLP kernel (edge MODE=0 / node MODE=1) ----------------
// 64 rows per block, 256 threads = 4 waves; wave w owns rows w*16..w*16+15.
// LDS: U = union{ Asm[64][328] | Hsm[64][136] (+ MODE1: n2g bins 32KB) },
// so edge=62.4KB, node=70.7KB -> 2 blocks/CU.
template <int MODE>
__global__ __launch_bounds__(256, 2) void mlp_kernel(
    const unsigned short* __restrict__ ebuf,  // MODE0: eb [NE][32]
    const unsigned short* __restrict__ xb,    // [NN][128]
    const unsigned short* __restrict__ ub,    // [NG][32]
    const float* __restrict__ aggsrc,         // MODE1: outE [NE][128] f32
    const int* __restrict__ rowIdx, const int* __restrict__ colIdx,
    const int* __restrict__ batch,
    const int* __restrict__ offs, const int* __restrict__ cnt,
    const int* __restrict__ eidlist,
    const unsigned short* __restrict__ W1T,   // [128][320] bf16
    const unsigned short* __restrict__ W2T,   // [128][128] bf16
    const float* __restrict__ b1, const float* __restrict__ b2,
    const float* __restrict__ gam, const float* __restrict__ bet,
    float* __restrict__ out, float* __restrict__ aggout, int nRows) {
  constexpr int USZ = (MODE == 1) ? 50176 : 41984;
  __shared__ __align__(16) char U[USZ];
  __shared__ __align__(16) unsigned short Bsm[128][72];
  __shared__ float cb1[128], cb2[128], cg[128], cbt[128];
  unsigned short (*Asm)[328] = (unsigned short(*)[328])U;   // 64 rows
  unsigned short (*Hsm)[136] = (unsigned short(*)[136])U;   // 64 rows
  float* bins = (float*)(U + 17408);                        // MODE1 only

  const int tid = threadIdx.x;
  if (tid < 128) {
    cb1[tid] = b1[tid]; cb2[tid] = b2[tid];
    cg[tid] = gam[tid]; cbt[tid] = bet[tid];
  }

  // ---- stage A tile: 4 threads per row ----
  {
    const int r = tid >> 2, q = tid & 3;
    const int grow = blockIdx.x * 64 + r;
    if (MODE == 0) {
      const int rcv = colIdx[grow];
      const int snd = rowIdx[grow];
      const int g = batch[snd];
      const uint4* esrc = (const uint4*)(ebuf + (size_t)grow * 32);
      const uint4* xr = (const uint4*)(xb + (size_t)rcv * 128);
      const uint4* xs = (const uint4*)(xb + (size_t)snd * 128);
      const uint4* us = (const uint4*)(ub + g * 32);
#pragma unroll
      for (int c = 0; c < 10; ++c) {
        const int cc = q * 10 + c;
        uint4 v;
        if (cc < 4)       v = esrc[cc];
        else if (cc < 20) v = xr[cc - 4];
        else if (cc < 36) v = xs[cc - 20];
        else              v = us[cc - 36];
        *(uint4*)&Asm[r][cc * 8] = v;
      }
    } else {
      const bool valid = grow < nRows;
      const uint4 zero = {0u, 0u, 0u, 0u};
      // x cols [q*32, q*32+32)
      if (valid) {
        const uint4* xs = (const uint4*)(xb + (size_t)grow * 128 + q * 32);
#pragma unroll
        for (int k = 0; k < 4; ++k) *(uint4*)&Asm[r][q * 32 + k * 8] = xs[k];
      } else {
#pragma unroll
        for (int k = 0; k < 4; ++k) *(uint4*)&Asm[r][q * 32 + k * 8] = zero;
      }
      // edge aggregation via CSR gather-sum, cols [128+q*32, 128+q*32+32)
      float4 a0{0,0,0,0}, a1{0,0,0,0}, a2{0,0,0,0}, a3{0,0,0,0};
      float4 a4{0,0,0,0}, a5{0,0,0,0}, a6{0,0,0,0}, a7{0,0,0,0};
      if (valid) {
        const int start = offs[grow];
        const int deg = cnt[grow];
        for (int j = 0; j < deg; ++j) {
          const int eid = eidlist[start + j];
          const float4* src = (const float4*)(aggsrc + (size_t)eid * 128 + q * 32);
          a0.x += src[0].x; a0.y += src[0].y; a0.z += src[0].z; a0.w += src[0].w;
          a1.x += src[1].x; a1.y += src[1].y; a1.z += src[1].z; a1.w += src[1].w;
          a2.x += src[2].x; a2.y += src[2].y; a2.z += src[2].z; a2.w += src[2].w;
          a3.x += src[3].x; a3.y += src[3].y; a3.z += src[3].z; a3.w += src[3].w;
          a4.x += src[4].x; a4.y += src[4].y; a4.z += src[4].z; a4.w += src[4].w;
          a5.x += src[5].x; a5.y += src[5].y; a5.z += src[5].z; a5.w += src[5].w;
          a6.x += src[6].x; a6.y += src[6].y; a6.z += src[6].z; a6.w += src[6].w;
          a7.x += src[7].x; a7.y += src[7].y; a7.z += src[7].z; a7.w += src[7].w;
        }
      }
      {
        const float4 av[8] = {a0, a1, a2, a3, a4, a5, a6, a7};
#pragma unroll
        for (int k = 0; k < 8; ++k) {
          ushort4 o;
          o.x = f2bf(av[k].x); o.y = f2bf(av[k].y);
          o.z = f2bf(av[k].z); o.w = f2bf(av[k].w);
          *(ushort4*)&Asm[r][128 + q * 32 + k * 4] = o;
        }
      }
      // u cols [256+q*8, 256+q*8+8)
      const int g = valid ? batch[grow] : 0;
      uint4 uv = valid ? *(const uint4*)(ub + g * 32 + q * 8) : zero;
      *(uint4*)&Asm[r][256 + q * 8] = uv;
      // pad cols [288+q*8, ...)
      *(uint4*)&Asm[r][288 + q * 8] = zero;
    }
  }

  const int w = tid >> 6;         // 0..3
  const int lane = tid & 63;
  const int l15 = lane & 15, lg = lane >> 4;

  f32x4 acc[8];
#pragma unroll
  for (int ni = 0; ni < 8; ++ni) acc[ni] = f32x4{0.f, 0.f, 0.f, 0.f};

  // ---- GEMM1: C1[64x128] = A[64x320] @ W1 ----
  for (int kc = 0; kc < 5; ++kc) {
    {
      const int n = tid >> 1, half = tid & 1;
      const uint4* src = (const uint4*)(W1T + (size_t)n * 320 + kc * 64 + half * 32);
#pragma unroll
      for (int k = 0; k < 4; ++k)
        *(uint4*)&Bsm[n][half * 32 + k * 8] = src[k];
    }
    __syncthreads();
    bf16x8 a0 = *(bf16x8*)&Asm[w * 16 + l15][kc * 64 + lg * 8];
    bf16x8 a1 = *(bf16x8*)&Asm[w * 16 + l15][kc * 64 + 32 + lg * 8];
#pragma unroll
    for (int ni = 0; ni < 8; ++ni) {
      bf16x8 bb0 = *(bf16x8*)&Bsm[ni * 16 + l15][lg * 8];
      bf16x8 bb1 = *(bf16x8*)&Bsm[ni * 16 + l15][32 + lg * 8];
      acc[ni] = __builtin_amdgcn_mfma_f32_16x16x32_bf16(a0, bb0, acc[ni], 0, 0, 0);
      acc[ni] = __builtin_amdgcn_mfma_f32_16x16x32_bf16(a1, bb1, acc[ni], 0, 0, 0);
    }
    __syncthreads();
  }

  // ---- h1 = relu(C1 + b1) -> Hsm (aliases dead Asm); MODE1: zero bins ----
#pragma unroll
  for (int ni = 0; ni < 8; ++ni) {
    const int ncol = l15 + ni * 16;
    const float bias = cb1[ncol];
#pragma unroll
    for (int reg = 0; reg < 4; ++reg) {
      const int mrow = w * 16 + lg * 4 + reg;
      Hsm[mrow][ncol] = f2bf(fmaxf(acc[ni][reg] + bias, 0.f));
    }
  }
  if (MODE == 1) {
    for (int i = tid; i < NG * 128; i += 256) bins[i] = 0.f;
  }

  // ---- GEMM2: C2 = H1[64x128] @ W2 ----
  f32x4 acc2[8];
#pragma unroll
  for (int ni = 0; ni < 8; ++ni) acc2[ni] = f32x4{0.f, 0.f, 0.f, 0.f};
  for (int kc = 0; kc < 2; ++kc) {
    {
      const int n = tid >> 1, half = tid & 1;
      const uint4* src = (const uint4*)(W2T + (size_t)n * 128 + kc * 64 + half * 32);
#pragma unroll
      for (int k = 0; k < 4; ++k)
        *(uint4*)&Bsm[n][half * 32 + k * 8] = src[k];
    }
    __syncthreads();  // covers Hsm writes + bins zero + Bsm restage
    bf16x8 a0 = *(bf16x8*)&Hsm[w * 16 + l15][kc * 64 + lg * 8];
    bf16x8 a1 = *(bf16x8*)&Hsm[w * 16 + l15][kc * 64 + 32 + lg * 8];
#pragma unroll
    for (int ni = 0; ni < 8; ++ni) {
      bf16x8 bb0 = *(bf16x8*)&Bsm[ni * 16 + l15][lg * 8];
      bf16x8 bb1 = *(bf16x8*)&Bsm[ni * 16 + l15][32 + lg * 8];
      acc2[ni] = __builtin_amdgcn_mfma_f32_16x16x32_bf16(a0, bb0, acc2[ni], 0, 0, 0);
      acc2[ni] = __builtin_amdgcn_mfma_f32_16x16x32_bf16(a1, bb1, acc2[ni], 0, 0, 0);
    }
    __syncthreads();
  }

  // ---- epilogue: bias + relu + LayerNorm + store (+ MODE1 n2g bins) ----
  float hv[8][4];
  float sreg[4] = {0.f, 0.f, 0.f, 0.f}, ssreg[4] = {0.f, 0.f, 0.f, 0.f};
#pragma unroll
  for (int ni = 0; ni < 8; ++ni) {
    const int ncol = l15 + ni * 16;
    const float bias = cb2[ncol];
#pragma unroll
    for (int reg = 0; reg < 4; ++reg) {
      const float h = fmaxf(acc2[ni][reg] + bias, 0.f);
      hv[ni][reg] = h;
      sreg[reg] += h; ssreg[reg] += h * h;
    }
  }
#pragma unroll
  for (int reg = 0; reg < 4; ++reg) {
    float s = sreg[reg], ss = ssreg[reg];
#pragma unroll
    for (int off = 1; off < 16; off <<= 1) {
      s += __shfl_xor(s, off, 64);
      ss += __shfl_xor(ss, off, 64);
    }
    sreg[reg] = s; ssreg[reg] = ss;
  }
#pragma unroll
  for (int reg = 0; reg < 4; ++reg) {
    const int mrow = w * 16 + lg * 4 + reg;
    const int grow = blockIdx.x * 64 + mrow;
    if (MODE == 1 && grow >= nRows) continue;
    const float mu = sreg[reg] * (1.f / 128.f);
    const float var = ssreg[reg] * (1.f / 128.f) - mu * mu;
    const float rstd = rsqrtf(var + EPSV);
    int g = 0;
    if (MODE == 1) g = batch[grow];
#pragma unroll
    for (int ni = 0; ni < 8; ++ni) {
      const int ncol = l15 + ni * 16;
      const float y = cg[ncol] * (hv[ni][reg] - mu) * rstd + cbt[ncol];
      out[(size_t)grow * 128 + ncol] = y;
      if (MODE == 1) atomicAdd(&bins[g * 128 + ncol], y);
    }
  }
  // MODE 1: flush block bins into n2g (batch sorted -> tiny [gmin,gmax] range)
  if (MODE == 1) {
    __syncthreads();
    const int first = blockIdx.x * 64;
    const int last = min(first + 63, nRows - 1);
    const int gmin = batch[first], gmax = batch[last];
    const int cntf = (gmax - gmin + 1) * 128;
    for (int i = tid; i < cntf; i += 256)
      atomicAdd(&aggout[gmin * 128 + i], bins[gmin * 128 + i]);
  }
}

// ---------------- edge->global segment sum (conflict-free bins) ----------------
__global__ __launch_bounds__(512) void seg_e2g_kernel(
    const float* __restrict__ data, const int* __restrict__ gid,
    float* __restrict__ part) {
  __shared__ float bins[NG * 128];
  const int t = threadIdx.x;
  for (int i = t; i < NG * 128; i += 512) bins[i] = 0.f;
  __syncthreads();
  const int chunk = NE / 256;  // 3125
  const int start = blockIdx.x * chunk;
  const int end = start + chunk;
  const int col = t & 127, sub = t >> 7;  // 4 subs of 128 threads
  for (int pos = start + sub; pos < end; pos += 4) {
    const int g = gid[pos];
    const float v = data[(size_t)pos * 128 + col];
    atomicAdd(&bins[g * 128 + col], v);
  }
  __syncthreads();
  float* dst = part + (size_t)blockIdx.x * (NG * 128);
  for (int i = t; i < NG * 128; i += 512) dst[i] = bins[i];
}

__global__ __launch_bounds__(256) void e2g_reduce_kernel(
    const float* __restrict__ part, float* __restrict__ e2g) {
  const int i = blockIdx.x * 256 + threadIdx.x;  // 8192 total
  float s = 0.f;
#pragma unroll 8
  for (int p = 0; p < 256; ++p) s += part[(size_t)p * (NG * 128) + i];
  e2g[i] = s;
}

// ---------------- global MLP (tiny) ----------------
__global__ __launch_bounds__(128) void glob_kernel(
    const float* __restrict__ u, const float* __restrict__ n2g,
    const float* __restrict__ e2g,
    const float* __restrict__ gW1, const float* __restrict__ gb1,
    const float* __restrict__ gW2, const float* __restrict__ gb2,
    const float* __restrict__ gg, const float* __restrict__ gbt,
    float* __restrict__ outU) {
  __shared__ float in[288];
  __shared__ float h1[128];
  __shared__ float red[4];
  const int g = blockIdx.x, t = threadIdx.x;
  if (t < 32) in[t] = u[g * 32 + t];
  in[32 + t] = n2g[g * 128 + t];
  in[160 + t] = e2g[g * 128 + t];
  __syncthreads();
  float a = gb1[t];
  for (int k = 0; k < 288; ++k) a += in[k] * gW1[k * 128 + t];
  h1[t] = fmaxf(a, 0.f);
  __syncthreads();
  float h = gb2[t];
  for (int k = 0; k < 128; ++k) h += h1[k] * gW2[k * 128 + t];
  h = fmaxf(h, 0.f);
  float s = h, ss = h * h;
  for (int off = 1; off < 64; off <<= 1) {
    s += __shfl_xor(s, off, 64);
    ss += __shfl_xor(ss, off, 64);
  }
  if ((t & 63) == 0) { red[(t >> 6) * 2] = s; red[(t >> 6) * 2 + 1] = ss; }
  __syncthreads();
  const float S = red[0] + red[2], SS = red[1] + red[3];
  const float mu = S * (1.f / 128.f);
  const float var = SS * (1.f / 128.f) - mu * mu;
  const float rstd = rsqrtf(var + EPSV);
  outU[g * 128 + t] = gg[t] * (h - mu) * rstd + gbt[t];
}

// ---------------- launch ----------------
extern "C" void kernel_launch(void* const* d_in, const int* in_sizes, int n_in,
                              void* d_out, int out_size, void* d_ws,
                              size_t ws_size, hipStream_t stream) {
  const float* x   = (const float*)d_in[0];
  const float* e   = (const float*)d_in[1];
  const float* u   = (const float*)d_in[2];
  const int* eidx  = (const int*)d_in[3];
  const int* batch = (const int*)d_in[4];
  const float* eW1 = (const float*)d_in[5];
  const float* eb1 = (const float*)d_in[6];
  const float* eW2 = (const float*)d_in[7];
  const float* eb2 = (const float*)d_in[8];
  const float* eg  = (const float*)d_in[9];
  const float* ebt = (const float*)d_in[10];
  const float* nW1 = (const float*)d_in[11];
  const float* nb1 = (const float*)d_in[12];
  const float* nW2 = (const float*)d_in[13];
  const float* nb2 = (const float*)d_in[14];
  const float* ng  = (const float*)d_in[15];
  const float* nbt = (const float*)d_in[16];
  const float* gW1 = (const float*)d_in[17];
  const float* gb1 = (const float*)d_in[18];
  const float* gW2 = (const float*)d_in[19];
  const float* gb2 = (const float*)d_in[20];
  const float* gg  = (const float*)d_in[21];
  const float* gbt = (const float*)d_in[22];

  char* ws = (char*)d_ws;
  float* e2g           = (float*)(ws + 0);          //    32,768
  float* n2g           = (float*)(ws + 32768);      //    32,768
  int*   cnt           = (int*)  (ws + 65536);      //   200,000
  int*   offs          = (int*)  (ws + 265536);     //   200,000
  int*   cur           = (int*)  (ws + 465536);     //   200,000
  int*   eidlist       = (int*)  (ws + 665536);     // 3,200,000
  int*   eg_arr        = (int*)  (ws + 3865536);    // 3,200,000
  float* e2g_part      = (float*)(ws + 7065536);    // 8,388,608
  unsigned short* xb   = (unsigned short*)(ws + 15454144);  // 12,800,000
  unsigned short* eb   = (unsigned short*)(ws + 28254144);  // 51,200,000
  unsigned short* ub   = (unsigned short*)(ws + 79454144);  //     4,096
  unsigned short* eW1T = (unsigned short*)(ws + 79458240);  //    81,920
  unsigned short* eW2T = (unsigned short*)(ws + 79540160);  //    32,768
  unsigned short* nW1T = (unsigned short*)(ws + 79572928);  //    81,920
  unsigned short* nW2T = (unsigned short*)(ws + 79654848);  //    32,768
  // total ws use: ~79.7 MB

  // zero e2g + n2g + cnt (contiguous)
  hipMemsetAsync(ws, 0, 265536, stream);

  cvt_vec_kernel<<<2048, 256, 0, stream>>>(x, e, xb, eb);
  cvt_small_kernel<<<456, 256, 0, stream>>>(u, eW1, eW2, nW1, nW2, ub, eW1T,
                                            eW2T, nW1T, nW2T);

  float* outX = (float*)d_out;                 // [50000][128]
  float* outE = outX + (size_t)NN * 128;       // [800000][128]
  float* outU = outE + (size_t)NE * 128;       // [64][128]

  const int* rowI = eidx;        // edge_index[0] (sender)
  const int* colI = eidx + NE;   // edge_index[1] (receiver)

  pre_kernel<<<(NE + 255) / 256, 256, 0, stream>>>(rowI, colI, batch, eg_arr, cnt);
  scan_kernel<<<1, 1024, 0, stream>>>(cnt, offs, cur);
  fill_kernel<<<(NE + 255) / 256, 256, 0, stream>>>(colI, cur, eidlist);

  mlp_kernel<0><<<NE / 64, 256, 0, stream>>>(
      eb, xb, ub, nullptr, rowI, colI, batch, nullptr, nullptr, nullptr,
      eW1T, eW2T, eb1, eb2, eg, ebt, outE, nullptr, NE);
  seg_e2g_kernel<<<256, 512, 0, stream>>>(outE, eg_arr, e2g_part);
  e2g_reduce_kernel<<<32, 256, 0, stream>>>(e2g_part, e2g);
  mlp_kernel<1><<<(NN + 63) / 64, 256, 0, stream>>>(
      nullptr, xb, ub, outE, nullptr, nullptr, batch, offs, cnt, eidlist,
      nW1T, nW2T, nb1, nb2, ng, nbt, outX, n2g, NN);
  glob_kernel<<<NG, 128, 0, stream>>>(u, n2g, e2g, gW1, gb1, gW2, gb2, gg, gbt,
                                      outU);
}